// Round 1
// baseline (576.085 us; speedup 1.0000x reference)
//
#include <hip/hip_runtime.h>
#include <math.h>

#define DM 4096
#define NEXP 64
#define BK 128
#define NC (DM / BK)          // 32 K-chunks
#define TOK_WG 64             // tokens per workgroup
#define TOK_WAVE 16           // tokens per wave

// lane = expert (64 experts == 64 lanes). Each wave computes 16 tokens x 64 experts.
// Ws: XOR-swizzled so ds_read_b128 of own row is conflict-free.
// Xs: linear; reads are wave-uniform -> LDS broadcast.
__global__ __launch_bounds__(256) void topk_router_kernel(
    const float* __restrict__ X,
    const float* __restrict__ W,
    const float* __restrict__ Bv,
    float* __restrict__ out)
{
    __shared__ float4 Ws[NEXP * (BK / 4)];   // 32 KiB
    __shared__ float4 Xs[TOK_WG * (BK / 4)]; // 32 KiB

    const int tid  = threadIdx.x;
    const int lane = tid & 63;
    const int wv   = tid >> 6;
    const int e7   = lane & 7;
    const long tok0 = (long)blockIdx.x * TOK_WG;

    const float4* __restrict__ Wg = (const float4*)W;
    const float4* __restrict__ Xg = (const float4*)X;

    float acc[TOK_WAVE];
#pragma unroll
    for (int j = 0; j < TOK_WAVE; ++j) acc[j] = 0.0f;

    const float bias = Bv[lane];

    float4 wreg[8], xreg[8];

    // ---- stage chunk 0 ----
#pragma unroll
    for (int i = 0; i < 8; ++i) {
        int u = tid + i * 256;
        int e = u >> 5, kg = u & 31;
        wreg[i] = Wg[e * (DM / 4) + kg];
    }
#pragma unroll
    for (int i = 0; i < 8; ++i) {
        int v = tid + i * 256;
        int t = v >> 5, kg = v & 31;
        xreg[i] = Xg[(tok0 + t) * (DM / 4) + kg];
    }
#pragma unroll
    for (int i = 0; i < 8; ++i) {
        int u = tid + i * 256;
        int e = u >> 5, kg = u & 31;
        Ws[e * 32 + (kg ^ (e & 7))] = wreg[i];
    }
#pragma unroll
    for (int i = 0; i < 8; ++i) {
        int v = tid + i * 256;
        int t = v >> 5, kg = v & 31;
        Xs[t * 32 + kg] = xreg[i];
    }
    __syncthreads();

#pragma unroll 1
    for (int c = 0; c < NC; ++c) {
        const bool pf = (c + 1 < NC);
        if (pf) {
            const int kg0 = (c + 1) * (BK / 4);
#pragma unroll
            for (int i = 0; i < 8; ++i) {
                int u = tid + i * 256;
                int e = u >> 5, kg = u & 31;
                wreg[i] = Wg[e * (DM / 4) + kg0 + kg];
            }
#pragma unroll
            for (int i = 0; i < 8; ++i) {
                int v = tid + i * 256;
                int t = v >> 5, kg = v & 31;
                xreg[i] = Xg[(tok0 + t) * (DM / 4) + kg0 + kg];
            }
        }

        // ---- compute this chunk ----
#pragma unroll 4
        for (int kk4 = 0; kk4 < BK / 4; ++kk4) {
            float4 w4 = Ws[lane * 32 + (kk4 ^ e7)];
#pragma unroll
            for (int j = 0; j < TOK_WAVE; ++j) {
                float4 x4 = Xs[(wv * TOK_WAVE + j) * 32 + kk4];
                acc[j] = fmaf(x4.x, w4.x, acc[j]);
                acc[j] = fmaf(x4.y, w4.y, acc[j]);
                acc[j] = fmaf(x4.z, w4.z, acc[j]);
                acc[j] = fmaf(x4.w, w4.w, acc[j]);
            }
        }
        __syncthreads();
        if (pf) {
#pragma unroll
            for (int i = 0; i < 8; ++i) {
                int u = tid + i * 256;
                int e = u >> 5, kg = u & 31;
                Ws[e * 32 + (kg ^ (e & 7))] = wreg[i];
            }
#pragma unroll
            for (int i = 0; i < 8; ++i) {
                int v = tid + i * 256;
                int t = v >> 5, kg = v & 31;
                Xs[t * 32 + kg] = xreg[i];
            }
            __syncthreads();
        }
    }

    // ---- epilogue: bias + softmax + top-2 + dense scatter ----
#pragma unroll 1
    for (int j = 0; j < TOK_WAVE; ++j) {
        float v = acc[j] + bias;

        // butterfly top-2 with indices (lower index wins ties, like lax.top_k)
        float m1 = v;        int i1 = lane;
        float m2 = -3.4e38f; int i2 = 127;
#pragma unroll
        for (int s = 1; s < 64; s <<= 1) {
            float om1 = __shfl_xor(m1, s, 64);
            int   oi1 = __shfl_xor(i1, s, 64);
            float om2 = __shfl_xor(m2, s, 64);
            int   oi2 = __shfl_xor(i2, s, 64);
            bool bw = (om1 > m1) || (om1 == m1 && oi1 < i1);
            float l1v = bw ? m1 : om1;  int l1i = bw ? i1 : oi1;  // loser of top
            float w2v = bw ? om2 : m2;  int w2i = bw ? oi2 : i2;  // winner's #2
            if (bw) { m1 = om1; i1 = oi1; }
            bool tw = (l1v > w2v) || (l1v == w2v && l1i < w2i);
            m2 = tw ? l1v : w2v;  i2 = tw ? l1i : w2i;
        }

        float p = expf(v - m1);
        float ssum = p;
#pragma unroll
        for (int s = 1; s < 64; s <<= 1) ssum += __shfl_xor(ssum, s, 64);

        float sc = (lane == i1 || lane == i2) ? (p / ssum) : 0.0f;
        out[(tok0 + wv * TOK_WAVE + j) * 64 + lane] = sc;
    }
}

extern "C" void kernel_launch(void* const* d_in, const int* in_sizes, int n_in,
                              void* d_out, int out_size, void* d_ws, size_t ws_size,
                              hipStream_t stream) {
    const float* X  = (const float*)d_in[0];   // [4,4096,4096] fp32
    const float* W  = (const float*)d_in[1];   // [64,4096] fp32
    const float* Bv = (const float*)d_in[2];   // [64] fp32
    float* out = (float*)d_out;                // [4,4096,64] fp32

    const int n_tokens = 4 * 4096;             // 16384
    dim3 grid(n_tokens / TOK_WG);              // 256 blocks
    dim3 block(256);
    topk_router_kernel<<<grid, block, 0, stream>>>(X, W, Bv, out);
}

// Round 3
// 83.980 us; speedup vs baseline: 6.8598x; 6.8598x over previous
//
#include <hip/hip_runtime.h>
#include <hip/hip_bf16.h>
#include <math.h>
#include <stdint.h>

#define DM 4096
#define NEXP 64
#define BK 64            // k per chunk
#define NCH (DM / BK)    // 64 chunks
#define TOKPB 16         // tokens per block

typedef short bf16x8 __attribute__((ext_vector_type(8)));
typedef float f32x4  __attribute__((ext_vector_type(4)));

// LDS: X planes [buf][plane][16 tok][8 granules*16B] = 2*2*16*128 = 8192 B.
// Logits (16 x 66 f32 = 4224 B) overlay the X region after the K-loop.
#define SMEM_BYTES 8192

// RN split: x = hi + lo + f, |f| <= 2^-18 |x|. lo = x - hi is Sterbenz-exact.
__device__ __forceinline__ void split2(float f0, float f1, uint32_t& hw, uint32_t& lw) {
    float2 ff; ff.x = f0; ff.y = f1;
    __hip_bfloat162 h = __float22bfloat162_rn(ff);
    union { __hip_bfloat162 b; uint32_t u; } ch; ch.b = h;
    hw = ch.u;
    float h0 = __bfloat162float(h.x);
    float h1 = __bfloat162float(h.y);
    float2 gg; gg.x = f0 - h0; gg.y = f1 - h1;
    __hip_bfloat162 l = __float22bfloat162_rn(gg);
    union { __hip_bfloat162 b; uint32_t u; } cl; cl.b = l;
    lw = cl.u;
}

// ---------------- pre-pass: W fp32 -> RN bf16 hi/lo, fragment-ordered blob ----------------
// blob byte layout: (c*2+h)*8192 + ks*4096 + n4*1024 + lane*16
// where lane = (e&15) | ((kgran&3)<<4), n4 = e>>4, ks = kgran>>2.
__global__ __launch_bounds__(512) void wsplit_kernel(const float* __restrict__ W,
                                                     char* __restrict__ blob) {
    const int c   = blockIdx.x;        // 0..63
    const int tid = threadIdx.x;       // 0..511
    const int e   = tid >> 3;          // expert 0..63
    const int g   = tid & 7;           // k-granule 0..7 (8 bf16 each)

    const float* src = W + (size_t)e * DM + c * BK + g * 8;
    float x[8];
    *(float4*)(x)     = *(const float4*)(src);
    *(float4*)(x + 4) = *(const float4*)(src + 4);

    uint32_t hiw[4], low[4];
#pragma unroll
    for (int j = 0; j < 4; ++j) split2(x[2 * j], x[2 * j + 1], hiw[j], low[j]);

    const int ks = g >> 2;
    const int ln = (e & 15) | ((g & 3) << 4);
    const int n4 = e >> 4;
    const size_t base = (size_t)c * 16384 + (size_t)ks * 4096 + (size_t)n4 * 1024 + (size_t)ln * 16;
    *(uint4*)(blob + base)        = *(uint4*)hiw;   // h=0 plane
    *(uint4*)(blob + base + 8192) = *(uint4*)low;   // h=1 plane
}

// ---------------- main kernel ----------------
__global__ __launch_bounds__(128) void router_mfma_kernel(
    const float* __restrict__ X,
    const char* __restrict__ blob,
    const float* __restrict__ Bv,
    float* __restrict__ out)
{
    __shared__ __align__(16) char smem[SMEM_BYTES];

    const int tid  = threadIdx.x;      // 0..127
    const int lane = tid & 63;
    const int wv   = tid >> 6;         // 0..1 (expert half)
    const long tok0 = (long)blockIdx.x * TOKPB;

    // X staging mapping: thread -> (token, k-granule)
    const int tkn = tid >> 3;          // 0..15
    const int kq  = tid & 7;           // 0..7
    const size_t rowbase = (size_t)(tok0 + tkn) * DM + kq * 8;

    f32x4 acc[2];
    acc[0] = (f32x4)0.0f;
    acc[1] = (f32x4)0.0f;

    float xa[8], xb[8];

    auto loadX = [&](float* xr, int c) {
        const float* p = X + rowbase + c * BK;
        *(float4*)(xr)     = *(const float4*)(p);
        *(float4*)(xr + 4) = *(const float4*)(p + 4);
    };

    auto cvtWrite = [&](const float* xr, int buf) {
        uint32_t hw[4], lw[4];
#pragma unroll
        for (int j = 0; j < 4; ++j) split2(xr[2 * j], xr[2 * j + 1], hw[j], lw[j]);
        const int slot = (kq ^ (tkn & 7)) * 16;
        char* bh = smem + ((buf * 2 + 0) * TOKPB + tkn) * 128;
        char* bl = smem + ((buf * 2 + 1) * TOKPB + tkn) * 128;
        *(uint4*)(bh + slot) = *(uint4*)hw;
        *(uint4*)(bl + slot) = *(uint4*)lw;
    };

    const int tk = lane & 15;          // token within tile (A row / C col mapping)
    const int kg = lane >> 4;          // 0..3 k-granule within 32-k
    const int sw = tk & 7;

    auto compute = [&](int buf, int c) {
        const char* bb = blob + (size_t)c * 16384;
#pragma unroll
        for (int ks = 0; ks < 2; ++ks) {
            const int gA   = ks * 4 + kg;
            const int slot = (gA ^ sw) * 16;
            bf16x8 ah = *(const bf16x8*)(smem + ((buf * 2 + 0) * TOKPB + tk) * 128 + slot);
            bf16x8 al = *(const bf16x8*)(smem + ((buf * 2 + 1) * TOKPB + tk) * 128 + slot);
#pragma unroll
            for (int n = 0; n < 2; ++n) {
                const int n4 = wv * 2 + n;
                const size_t bo = (size_t)ks * 4096 + (size_t)n4 * 1024 + (size_t)lane * 16;
                bf16x8 bh = *(const bf16x8*)(bb + bo);
                bf16x8 bl = *(const bf16x8*)(bb + 8192 + bo);
                acc[n] = __builtin_amdgcn_mfma_f32_16x16x32_bf16(ah, bh, acc[n], 0, 0, 0);
                acc[n] = __builtin_amdgcn_mfma_f32_16x16x32_bf16(ah, bl, acc[n], 0, 0, 0);
                acc[n] = __builtin_amdgcn_mfma_f32_16x16x32_bf16(al, bh, acc[n], 0, 0, 0);
                acc[n] = __builtin_amdgcn_mfma_f32_16x16x32_bf16(al, bl, acc[n], 0, 0, 0);
            }
        }
    };

    // ---- prologue ----
    loadX(xa, 0);
    cvtWrite(xa, 0);
    __syncthreads();

    // ---- main loop: 2 chunks per iteration, ping-pong LDS buffers & reg sets ----
#pragma unroll 1
    for (int cc = 0; cc < NCH / 2; ++cc) {
        const int c0 = 2 * cc;
        loadX(xb, c0 + 1);
        compute(0, c0);
        cvtWrite(xb, 1);
        __syncthreads();
        if (cc + 1 < NCH / 2) {
            loadX(xa, c0 + 2);
            compute(1, c0 + 1);
            cvtWrite(xa, 0);
        } else {
            compute(1, c0 + 1);
        }
        __syncthreads();
    }

    // ---- logits to LDS (overlay X region): C layout col=lane&15, row=(lane>>4)*4+r ----
#pragma unroll
    for (int n = 0; n < 2; ++n) {
        const int ee = (wv * 2 + n) * 16 + tk;
#pragma unroll
        for (int r = 0; r < 4; ++r) {
            const int tl = kg * 4 + r;
            *(float*)(smem + tl * 264 + ee * 4) = acc[n][r];
        }
    }
    __syncthreads();

    // ---- epilogue: bias + softmax + top-2 + dense scatter (lane = expert) ----
    const float bias = Bv[lane];
#pragma unroll 1
    for (int j = 0; j < 8; ++j) {
        const int t = wv * 8 + j;
        float v = *(const float*)(smem + t * 264 + lane * 4) + bias;

        float m1 = v;        int i1 = lane;
        float m2 = -3.4e38f; int i2 = 127;
#pragma unroll
        for (int s = 1; s < 64; s <<= 1) {
            float om1 = __shfl_xor(m1, s, 64);
            int   oi1 = __shfl_xor(i1, s, 64);
            float om2 = __shfl_xor(m2, s, 64);
            int   oi2 = __shfl_xor(i2, s, 64);
            bool bw = (om1 > m1) || (om1 == m1 && oi1 < i1);
            float l1v = bw ? m1 : om1;  int l1i = bw ? i1 : oi1;
            float w2v = bw ? om2 : m2;  int w2i = bw ? oi2 : i2;
            if (bw) { m1 = om1; i1 = oi1; }
            bool tw = (l1v > w2v) || (l1v == w2v && l1i < w2i);
            m2 = tw ? l1v : w2v;  i2 = tw ? l1i : w2i;
        }

        float p = expf(v - m1);
        float ssum = p;
#pragma unroll
        for (int s = 1; s < 64; s <<= 1) ssum += __shfl_xor(ssum, s, 64);

        float sc = (lane == i1 || lane == i2) ? (p / ssum) : 0.0f;
        out[(size_t)(tok0 + t) * NEXP + lane] = sc;
    }
}

extern "C" void kernel_launch(void* const* d_in, const int* in_sizes, int n_in,
                              void* d_out, int out_size, void* d_ws, size_t ws_size,
                              hipStream_t stream) {
    const float* X  = (const float*)d_in[0];   // [4,4096,4096] fp32
    const float* W  = (const float*)d_in[1];   // [64,4096] fp32
    const float* Bv = (const float*)d_in[2];   // [64] fp32
    float* out = (float*)d_out;                // [4,4096,64] fp32

    // W split blob: 64 chunks * 2 planes * 8192 B = 1 MiB in d_ws
    char* blob = (char*)d_ws;
    wsplit_kernel<<<dim3(NCH), dim3(512), 0, stream>>>(W, blob);

    const int n_tokens = 4 * 4096;             // 16384
    router_mfma_kernel<<<dim3(n_tokens / TOKPB), dim3(128), 0, stream>>>(X, blob, Bv, out);
}